// Round 3
// baseline (486.706 us; speedup 1.0000x reference)
//
#include <hip/hip_runtime.h>

// RouterModel: top-1-of-2 softmax router with dense dispatch.
//   score = softmax(x @ W)          [N,2]
//   path  = argmax(score)           (tie -> 0, numpy first-occurrence)
//   x0 = x * (path==0 ? p0 : 0); x1 = x * (path==1 ? p1 : 0); xc = x0 + x1
//
// Pass 1: per-token gates (read-only stream). Pass 2: dispatch with
// FILL-LIKE writes: each block covers 16 token rows (64 KB), holds them in
// registers, then writes each output stream in a separate contiguous 64 KB
// burst (o0 fully, then o1, then oc) instead of interleaving the three
// streams at 1 KB granularity. Round-2 A/B showed x stays L3-resident
// between passes (re-read cost ~0), so pass-2 reads are cheap; the target
// is write-stream burst length, the one structural difference vs the
// 6.3 TB/s fillBuffer kernel.

constexpr int kN = 32768;
constexpr int kD = 1024;
constexpr long long kND = (long long)kN * kD;

// clang-native 4-float vector: __builtin_nontemporal_store requires a native
// vector type (HIP's float4 class is rejected).
typedef float f32x4 __attribute__((ext_vector_type(4)));

// ---------------------------------------------------------------------------
// Pass 1: one wave (64 lanes) per token. Lane l holds float4 indices
// {l, l+64, l+128, l+192} of the 256-float4 row: coalesced 16B/lane loads.
// Butterfly-reduce the two dot products, softmax+argmax, lane 0 writes the
// gate pair {g0, g1}.
__global__ __launch_bounds__(256) void router_score(
    const float* __restrict__ x, const float* __restrict__ W,
    float2* __restrict__ gates)
{
    const int wave_in_blk = threadIdx.x >> 6;
    const int lane        = threadIdx.x & 63;
    const int t           = blockIdx.x * 4 + wave_in_blk;   // token id

    const float4* __restrict__ row4 = (const float4*)(x + (long long)t * kD);
    const float4* __restrict__ W4   = (const float4*)W;     // interleaved [D,2]

    float s0 = 0.f, s1 = 0.f;
#pragma unroll
    for (int j = 0; j < 4; ++j) {
        const int idx = lane + j * 64;          // float4 index within row
        const float4 v  = row4[idx];
        const float4 wa = W4[2 * idx];          // {W0[d],W1[d],W0[d+1],W1[d+1]}
        const float4 wb = W4[2 * idx + 1];      // {W0[d+2],W1[d+2],W0[d+3],W1[d+3]}
        s0 += v.x * wa.x + v.y * wa.z + v.z * wb.x + v.w * wb.z;
        s1 += v.x * wa.y + v.y * wa.w + v.z * wb.y + v.w * wb.w;
    }

#pragma unroll
    for (int off = 32; off >= 1; off >>= 1) {
        s0 += __shfl_xor(s0, off, 64);
        s1 += __shfl_xor(s1, off, 64);
    }

    if (lane == 0) {
        const float m   = fmaxf(s0, s1);
        const float e0  = expf(s0 - m);
        const float e1  = expf(s1 - m);
        const float inv = 1.f / (e0 + e1);
        const float p0  = e0 * inv;
        const float p1  = e1 * inv;
        const int path  = (s1 > s0) ? 1 : 0;    // tie -> 0, matches jnp.argmax
        gates[t] = make_float2(path == 0 ? p0 : 0.f,
                               path == 1 ? p1 : 0.f);
    }
}

// ---------------------------------------------------------------------------
// Pass 2: 16 tokens per 256-thread block (grid 2048). For a given k, all 256
// threads (64 float4s x 4 waves... 256 float4 = one 1024-float row) cover
// exactly row k of the block's 16-row chunk -> gate is block-uniform
// (scalar load, SGPR operand to the multiply). Row data lives in 16
// f32x4 registers per thread; each output stream is then written as one
// contiguous ascending 64 KB burst per block.
constexpr int kTok = 16;

__global__ __launch_bounds__(256) void router_dispatch(
    const float* __restrict__ x, const float2* __restrict__ gates,
    float* __restrict__ out)
{
    const int tid = threadIdx.x;
    const long long base4 = (long long)blockIdx.x * (kTok * 256) + tid; // float4 units
    const f32x4* __restrict__ x4 = (const f32x4*)x;
    f32x4* __restrict__ o0 = (f32x4*)out;
    f32x4* __restrict__ o1 = (f32x4*)(out + kND);
    f32x4* __restrict__ oc = (f32x4*)(out + 2 * kND);

    // 16 row-slices in flight (256 B/thread outstanding loads).
    f32x4 v[kTok];
#pragma unroll
    for (int k = 0; k < kTok; ++k) v[k] = x4[base4 + k * 256];

    // Block-uniform gates -> scalar loads / SGPRs.
    const int t0 = blockIdx.x * kTok;
    float g0[kTok], g1[kTok];
#pragma unroll
    for (int k = 0; k < kTok; ++k) {
        const float2 g = gates[t0 + k];
        g0[k] = g.x;
        g1[k] = g.y;
    }

    // Three fill-like bursts: 64 KB contiguous per stream per block.
#pragma unroll
    for (int k = 0; k < kTok; ++k)
        __builtin_nontemporal_store(v[k] * g0[k], &o0[base4 + k * 256]);
#pragma unroll
    for (int k = 0; k < kTok; ++k)
        __builtin_nontemporal_store(v[k] * g1[k], &o1[base4 + k * 256]);
#pragma unroll
    for (int k = 0; k < kTok; ++k)
        __builtin_nontemporal_store(v[k] * (g0[k] + g1[k]), &oc[base4 + k * 256]);
}

extern "C" void kernel_launch(void* const* d_in, const int* in_sizes, int n_in,
                              void* d_out, int out_size, void* d_ws, size_t ws_size,
                              hipStream_t stream)
{
    const float* x = (const float*)d_in[0];   // [N, D] fp32
    const float* W = (const float*)d_in[1];   // [D, 2] fp32
    float* out     = (float*)d_out;           // x0 | x1 | xc, each [N, D]
    float2* gates  = (float2*)d_ws;           // [N] gate pairs, 256 KB

    router_score<<<kN / 4, 256, 0, stream>>>(x, W, gates);
    router_dispatch<<<kN / kTok, 256, 0, stream>>>(x, gates, out);
}